// Round 10
// baseline (288.301 us; speedup 1.0000x reference)
//
#include <hip/hip_runtime.h>

#define N_NODES 50000
#define C_FEAT  64
#define E_EDGES 800000
#define KEYS    400000          // dst*8 + t
#define NBLK1   391             // ceil(KEYS/1024)
#define DPB     16              // dsts per conv tile -> 16 MFMA rows
#define NTILES  (N_NODES / DPB) // 3125
#define PBLK_X  1563            // x->bf16 cvt blocks (8 elems/thread, last partial)
#define PBLK_W  128             // Wt transpose blocks
#define PBLK_A  64              // Wa1T/Wa2T transpose blocks (2 x 8192)
#define PBLK_H  391             // hist blocks: single pass, 2048 edges/block
#define DPART   6250            // dsts per XCD partition (scatter)
#define CONV_GRID 1024          // persistent: 4 blocks/CU x 256 CU
#define RS      516             // scatf row stride (floats): 512 + 4 pad

typedef __attribute__((ext_vector_type(8))) short short8;
typedef __attribute__((ext_vector_type(4))) float f32x4;

__device__ __forceinline__ float bf2f(unsigned short u) {
    union { unsigned int i; float f; } v; v.i = ((unsigned int)u) << 16; return v.f;
}
__device__ __forceinline__ unsigned short f2bf(float f) {
    union { float f; unsigned int i; } v; v.f = f;
    unsigned int r = v.i + 0x7fff + ((v.i >> 16) & 1);   // RNE
    return (unsigned short)(r >> 16);
}

// -------- prep (x->bf16, Wt->WT bf16, Wa->WaT bf16) + single-pass hist --------
__global__ __launch_bounds__(256) void prep_hist(const float* __restrict__ x,
                                                 const float* __restrict__ W1,
                                                 const float* __restrict__ W2,
                                                 const float* __restrict__ Wa1,
                                                 const float* __restrict__ Wa2,
                                                 const int* __restrict__ dst,
                                                 const int* __restrict__ tix,
                                                 unsigned short* __restrict__ xb,
                                                 unsigned short* __restrict__ WT1,
                                                 unsigned short* __restrict__ WT2,
                                                 unsigned short* __restrict__ Wa1T,
                                                 unsigned short* __restrict__ Wa2T,
                                                 int* __restrict__ cnt) {
    const int b = blockIdx.x;
    if (b < PBLK_X) {
        int base = (b * 256 + threadIdx.x) * 8;
        if (base < N_NODES * 64) {
            float4 a = *(const float4*)(x + base);
            float4 c = *(const float4*)(x + base + 4);
            short8 o;
            o[0] = (short)f2bf(a.x); o[1] = (short)f2bf(a.y);
            o[2] = (short)f2bf(a.z); o[3] = (short)f2bf(a.w);
            o[4] = (short)f2bf(c.x); o[5] = (short)f2bf(c.y);
            o[6] = (short)f2bf(c.z); o[7] = (short)f2bf(c.w);
            *(short8*)(xb + base) = o;
        }
    } else if (b < PBLK_X + PBLK_W) {
        int i = (b - PBLK_X) * 256 + threadIdx.x;      // 32768
        int n = i >> 9, k = i & 511;
        WT1[i] = f2bf(W1[k * 64 + n]);
        WT2[i] = f2bf(W2[k * 64 + n]);
    } else if (b < PBLK_X + PBLK_W + PBLK_A) {
        int i = (b - PBLK_X - PBLK_W) * 256 + threadIdx.x;   // 0..16383
        if (i < 8192) {                                // Wa1T[128][64] <- Wa1[64][128]
            int n = i >> 6, k = i & 63;
            Wa1T[i] = f2bf(Wa1[k * 128 + n]);
        } else {                                       // Wa2T[64][128] <- Wa2[128][64]
            int ii = i - 8192;
            int n = ii >> 7, k = ii & 127;
            Wa2T[ii] = f2bf(Wa2[k * 64 + n]);
        }
    } else {
        // single-pass hist: every edge visited once; atomics fire-and-forget
        int bb = b - PBLK_X - PBLK_W - PBLK_A;         // 0..390
        const int e0 = bb * 2048 + threadIdx.x * 8;
        if (e0 < E_EDGES) {                            // E%8==0 -> window fully in-bounds
            int4 d0 = *(const int4*)(dst + e0);
            int4 d1 = *(const int4*)(dst + e0 + 4);
            int4 t0 = *(const int4*)(tix + e0);
            int4 t1 = *(const int4*)(tix + e0 + 4);
            int dd[8] = {d0.x, d0.y, d0.z, d0.w, d1.x, d1.y, d1.z, d1.w};
            int tt[8] = {t0.x, t0.y, t0.z, t0.w, t1.x, t1.y, t1.z, t1.w};
            #pragma unroll
            for (int k = 0; k < 8; ++k)
                atomicAdd(&cnt[dd[k] * 8 + tt[k]], 1);
        }
    }
}

// -------- scan_all: per-chunk local scan; LAST block scans chunk totals --------
__global__ __launch_bounds__(256) void scan_all(int* __restrict__ cnt,
                                                int* __restrict__ bsum,
                                                int* __restrict__ chunkoff,
                                                int* __restrict__ done) {
    __shared__ int wsum[4];
    __shared__ int ticket;
    const int tid = threadIdx.x;
    const int lane = tid & 63;
    const int wave = tid >> 6;
    const int i4 = blockIdx.x * 256 + tid;
    int4 v = make_int4(0, 0, 0, 0);
    const bool ok = (i4 * 4 < KEYS);
    if (ok) v = ((const int4*)cnt)[i4];
    int s = v.x + v.y + v.z + v.w;
    int sc = s;
    #pragma unroll
    for (int d = 1; d < 64; d <<= 1) {
        int o = __shfl_up(sc, d, 64);
        if (lane >= d) sc += o;
    }
    if (lane == 63) wsum[wave] = sc;
    __syncthreads();
    int wbase = 0;
    #pragma unroll
    for (int w = 0; w < 4; ++w) wbase += (w < wave) ? wsum[w] : 0;
    int base = wbase + sc - s;
    int4 o;
    o.x = base;
    o.y = base + v.x;
    o.z = o.y + v.y;
    o.w = o.z + v.z;
    if (ok) ((int4*)cnt)[i4] = o;
    if (tid == 255) {
        bsum[blockIdx.x] = wbase + sc;
        __threadfence();
        ticket = atomicAdd(done, 1);
    }
    __syncthreads();
    if (ticket == NBLK1 - 1 && wave == 0) {
        int carry = 0;
        #pragma unroll
        for (int g = 0; g < (NBLK1 + 63) / 64; ++g) {
            int j = g * 64 + lane;
            int val = (j < NBLK1) ? atomicAdd(&bsum[j], 0) : 0;
            int scn = val;
            #pragma unroll
            for (int d = 1; d < 64; d <<= 1) {
                int oo = __shfl_up(scn, d, 64);
                if (lane >= d) scn += oo;
            }
            if (j < NBLK1) chunkoff[j] = carry + scn - val;
            carry += __shfl(scn, 63, 64);
        }
    }
}

// -------- XCD-partitioned scatter (8-pass, proven): elist word carries dlocal --------
__global__ __launch_bounds__(256) void scatter_edges(const int* __restrict__ src,
                                                     const int* __restrict__ dst,
                                                     const int* __restrict__ tix,
                                                     int* __restrict__ cursor,
                                                     const int* __restrict__ chunkoff,
                                                     int* __restrict__ elist) {
    const int g = blockIdx.x & 7;                    // partition (XCD-affine)
    const int lo = g * DPART;
    const int e0 = (blockIdx.x >> 3) * 2048 + threadIdx.x * 8;
    if (e0 < E_EDGES) {                              // E%8==0 -> window fully in-bounds
        int4 d0 = *(const int4*)(dst + e0);
        int4 d1 = *(const int4*)(dst + e0 + 4);
        int4 t0 = *(const int4*)(tix + e0);
        int4 t1 = *(const int4*)(tix + e0 + 4);
        int4 s0 = *(const int4*)(src + e0);
        int4 s1 = *(const int4*)(src + e0 + 4);
        int dd[8] = {d0.x, d0.y, d0.z, d0.w, d1.x, d1.y, d1.z, d1.w};
        int tt[8] = {t0.x, t0.y, t0.z, t0.w, t1.x, t1.y, t1.z, t1.w};
        int ss[8] = {s0.x, s0.y, s0.z, s0.w, s1.x, s1.y, s1.z, s1.w};
        #pragma unroll
        for (int k = 0; k < 8; ++k) {
            if ((unsigned)(dd[k] - lo) < (unsigned)DPART) {
                int key = dd[k] * 8 + tt[k];
                int pos = chunkoff[key >> 10] + atomicAdd(&cursor[key], 1);
                elist[pos] = ss[k] | (tt[k] << 16) | ((dd[k] & 15) << 19);
            }
        }
    }
}

// -------- fused conv: persistent, 8 waves x EQUAL edge slices, f32 LDS acc, MFMA --------
// Tile's 128 keys = one contiguous elist range; split into 8 equal edge-count
// slices (not per-dst) -> every wave processes ~cntE/8 edges (kills the
// max-of-8 Poisson imbalance that inflated the barrier wait ~1.5x).
// Boundary keys (split across waves) handled by LDS f32 atomicAdd on only the
// FIRST and FINAL flush of each slice (<=16 ds_add_f32 per tile); interior
// keys are wave-owned -> plain stores, exactly as before.
#define FLUSH(P, V)                                                                   \
    { int _k = (P) >> 16;                                                             \
      if (_k != cur) {                                                               \
          float* sp = scatf + (cur >> 3) * RS + (cur & 7) * 64 + c;                   \
          if (first) { atomicAdd(sp, acc); first = false; } else *sp = acc;           \
          acc = 0.f; cur = _k; }                                                      \
      acc += (V); }

#define EDGE(K)                                                                       \
    int p##K = __builtin_amdgcn_readlane(pv, e + K);                                  \
    float v##K = bf2f(Xb[(size_t)(p##K & 0xffff) * 64 + c]);

template <bool ADV>
__global__ __launch_bounds__(512, 8) void fused_conv(const unsigned short* __restrict__ Xb,
                                                     const unsigned short* __restrict__ WT,
                                                     const float* __restrict__ bias,
                                                     const int* __restrict__ segend,   // local ends
                                                     const int* __restrict__ chunkoff,
                                                     const int* __restrict__ elist,
                                                     unsigned short* __restrict__ Hb,
                                                     const unsigned short* __restrict__ Wa1T,
                                                     const float* __restrict__ ba1,
                                                     const unsigned short* __restrict__ Wa2T,
                                                     const float* __restrict__ ba2,
                                                     const unsigned short* __restrict__ h1r,
                                                     float* __restrict__ outF) {
    __shared__ __attribute__((aligned(16))) float scatf[DPB * RS];   // 33024 B
    // adv-phase aliases over the scatf pool (used only after a barrier)
    unsigned short (*sH)[72]  = (unsigned short(*)[72])scatf;                  // 2304 B
    unsigned short (*sT)[136] = (unsigned short(*)[136])((char*)scatf + 4096); // 4352 B
    const int lane = threadIdx.x & 63;
    const int wave = threadIdx.x >> 6;               // 0..7
    const int tid  = threadIdx.x;
    const int c = lane;

    for (int tile = blockIdx.x; tile < NTILES; tile += CONV_GRID) {
        const int dbase = tile * DPB;

        {   // zero scatf cooperatively (f32x4), then barrier (rows are cross-wave now)
            f32x4 z = {0.f, 0.f, 0.f, 0.f};
            #pragma unroll
            for (int j = tid; j < DPB * RS / 4; j += 512)
                *(f32x4*)&scatf[j * 4] = z;
        }

        // tile's contiguous edge range over keys [dbase*8, dbase*8+128)
        const int k0 = dbase * 8;
        const int beg = (dbase == 0) ? 0 : chunkoff[(k0 - 1) >> 10] + segend[k0 - 1];
        const int end = chunkoff[(k0 + 127) >> 10] + segend[k0 + 127];
        const int cntE = end - beg;
        const int pw = (cntE + 7) >> 3;              // equal split across 8 waves
        int wbeg = beg + wave * pw;
        int wend = wbeg + pw;
        if (wbeg > end) wbeg = end;
        if (wend > end) wend = end;

        __syncthreads();                             // scatf zeroed before any flush

        if (wbeg < wend) {
            int pv = (lane < wend - wbeg) ? elist[wbeg + lane] : 0;
            int i = wbeg;
            int cur = __builtin_amdgcn_readlane(pv, 0) >> 16;
            float acc = 0.f;
            bool first = true;
            while (i < wend) {
                int cnt = wend - i; cnt = (cnt > 64) ? 64 : cnt;
                int pvn = 0;
                if (i + 64 < wend) pvn = (lane < wend - i - 64) ? elist[i + 64 + lane] : 0;
                int e = 0;
                for (; e + 15 < cnt; e += 16) {          // 16 gathers in flight
                    EDGE(0)  EDGE(1)  EDGE(2)  EDGE(3)
                    EDGE(4)  EDGE(5)  EDGE(6)  EDGE(7)
                    EDGE(8)  EDGE(9)  EDGE(10) EDGE(11)
                    EDGE(12) EDGE(13) EDGE(14) EDGE(15)
                    FLUSH(p0, v0)   FLUSH(p1, v1)   FLUSH(p2, v2)   FLUSH(p3, v3)
                    FLUSH(p4, v4)   FLUSH(p5, v5)   FLUSH(p6, v6)   FLUSH(p7, v7)
                    FLUSH(p8, v8)   FLUSH(p9, v9)   FLUSH(p10, v10) FLUSH(p11, v11)
                    FLUSH(p12, v12) FLUSH(p13, v13) FLUSH(p14, v14) FLUSH(p15, v15)
                }
                if (e + 7 < cnt) {                       // tail tier 8
                    EDGE(0) EDGE(1) EDGE(2) EDGE(3) EDGE(4) EDGE(5) EDGE(6) EDGE(7)
                    FLUSH(p0, v0) FLUSH(p1, v1) FLUSH(p2, v2) FLUSH(p3, v3)
                    FLUSH(p4, v4) FLUSH(p5, v5) FLUSH(p6, v6) FLUSH(p7, v7)
                    e += 8;
                }
                if (e + 3 < cnt) {                       // tail tier 4
                    EDGE(0) EDGE(1) EDGE(2) EDGE(3)
                    FLUSH(p0, v0) FLUSH(p1, v1) FLUSH(p2, v2) FLUSH(p3, v3)
                    e += 4;
                }
                if (e + 1 < cnt) {                       // tail tier 2
                    EDGE(0) EDGE(1)
                    FLUSH(p0, v0) FLUSH(p1, v1)
                    e += 2;
                }
                if (e < cnt) {                           // tail tier 1
                    EDGE(0)
                    FLUSH(p0, v0)
                }
                i += 64;
                pv = pvn;
            }
            // final flush: slice's last key may be shared with next wave -> atomic
            float* sp = scatf + (cur >> 3) * RS + (cur & 7) * 64 + c;
            atomicAdd(sp, acc);
        }
        __syncthreads();

        // MFMA [16,512]@[512,64] on waves 0..3; C/D col=lane&15, row=quad*4+r (m89/m91)
        const int m = lane & 15;
        const int quad = lane >> 4;
        f32x4 acc4 = {0.f, 0.f, 0.f, 0.f};
        if (wave < 4) {
            const int n0 = wave * 16;
            const unsigned short* wrow = WT + (size_t)(n0 + m) * 512;
            const float* arow = scatf + m * RS;
            #pragma unroll
            for (int kc = 0; kc < 16; ++kc) {
                f32x4 a0 = *(const f32x4*)(arow + kc * 32 + quad * 8);
                f32x4 a1 = *(const f32x4*)(arow + kc * 32 + quad * 8 + 4);
                short8 af;
                af[0] = (short)f2bf(a0.x); af[1] = (short)f2bf(a0.y);
                af[2] = (short)f2bf(a0.z); af[3] = (short)f2bf(a0.w);
                af[4] = (short)f2bf(a1.x); af[5] = (short)f2bf(a1.y);
                af[6] = (short)f2bf(a1.z); af[7] = (short)f2bf(a1.w);
                short8 bf = *(const short8*)(wrow + kc * 32 + quad * 8);
                acc4 = __builtin_amdgcn_mfma_f32_16x16x32_bf16(af, bf, acc4, 0, 0, 0);
            }
        }

        if (!ADV) {
            if (wave < 4) {
                const int col = wave * 16 + m;
                const float bcol = bias[col];
                #pragma unroll
                for (int r = 0; r < 4; ++r) {
                    int node = dbase + quad * 4 + r;
                    Hb[(size_t)node * 64 + col] = f2bf(fmaxf(acc4[r] + bcol, 0.f));
                }
            }
        } else {
            // ---- fused adversary MLP on this tile's 16 nodes ----
            __syncthreads();                     // all scatf MFMA reads complete
            if (wave < 4) {                      // h2 (relu'd, bf16) -> sH
                const int col = wave * 16 + m;
                const float bcol = bias[col];
                #pragma unroll
                for (int r = 0; r < 4; ++r)
                    sH[quad * 4 + r][col] = f2bf(fmaxf(acc4[r] + bcol, 0.f));
            }
            __syncthreads();
            {   // GEMM1: [16,64]@[64,128]; 8 waves, one 16-col tile each
                f32x4 a1 = {0.f, 0.f, 0.f, 0.f};
                const int col = wave * 16 + m;
                #pragma unroll
                for (int kc = 0; kc < 2; ++kc) {
                    short8 af = *(const short8*)&sH[m][kc * 32 + quad * 8];
                    short8 bf = *(const short8*)(Wa1T + (size_t)col * 64 + kc * 32 + quad * 8);
                    a1 = __builtin_amdgcn_mfma_f32_16x16x32_bf16(af, bf, a1, 0, 0, 0);
                }
                const float b1 = ba1[col];
                #pragma unroll
                for (int r = 0; r < 4; ++r)
                    sT[quad * 4 + r][col] = f2bf(fmaxf(a1[r] + b1, 0.f));
            }
            __syncthreads();
            if (wave < 4) {                      // GEMM2: [16,128]@[128,64] + ba2 + h1
                f32x4 a2 = {0.f, 0.f, 0.f, 0.f};
                const int col = wave * 16 + m;
                #pragma unroll
                for (int kc = 0; kc < 4; ++kc) {
                    short8 af = *(const short8*)&sT[m][kc * 32 + quad * 8];
                    short8 bf = *(const short8*)(Wa2T + (size_t)col * 128 + kc * 32 + quad * 8);
                    a2 = __builtin_amdgcn_mfma_f32_16x16x32_bf16(af, bf, a2, 0, 0, 0);
                }
                const float b2 = ba2[col];
                #pragma unroll
                for (int r = 0; r < 4; ++r) {
                    int node = dbase + quad * 4 + r;
                    outF[(size_t)node * 64 + col] =
                        a2[r] + b2 + bf2f(h1r[(size_t)node * 64 + col]);
                }
            }
        }
        __syncthreads();   // all LDS readers done before next tile's zeroing
    }
}

extern "C" void kernel_launch(void* const* d_in, const int* in_sizes, int n_in,
                              void* d_out, int out_size, void* d_ws, size_t ws_size,
                              hipStream_t stream) {
    const float* x   = (const float*)d_in[0];
    const int*   ei  = (const int*)d_in[1];
    const int*   tix = (const int*)d_in[2];
    const float* Wt1 = (const float*)d_in[3];
    const float* bt1 = (const float*)d_in[4];
    const float* Wt2 = (const float*)d_in[5];
    const float* bt2 = (const float*)d_in[6];
    const float* Wa1 = (const float*)d_in[7];
    const float* ba1 = (const float*)d_in[8];
    const float* Wa2 = (const float*)d_in[9];
    const float* ba2 = (const float*)d_in[10];
    float* out = (float*)d_out;

    const int* src = ei;
    const int* dst = ei + E_EDGES;

    // workspace (~25 MB)
    unsigned short* xb   = (unsigned short*)d_ws;          // [N,64] bf16
    unsigned short* h1b  = xb + (size_t)N_NODES * 64;      // [N,64] bf16
    unsigned short* h2b  = h1b + (size_t)N_NODES * 64;     // [N,64] bf16 (unused now)
    unsigned short* WT1  = h2b + (size_t)N_NODES * 64;     // [64,512] bf16
    unsigned short* WT2  = WT1 + 64 * 512;
    unsigned short* Wa1T = WT2 + 64 * 512;                 // [128,64] bf16
    unsigned short* Wa2T = Wa1T + 8192;                    // [64,128] bf16
    int* cnt      = (int*)(Wa2T + 8192);                   // KEYS
    int* bsum     = cnt + KEYS;                            // 512
    int* chunkoff = bsum + 512;                            // 512
    int* done     = chunkoff + 512;                        // 64 (1 used)
    int* elist    = done + 64;                             // E packed (src | t<<16 | dl<<19)

    hipMemsetAsync(cnt, 0, (KEYS + 512 + 512 + 64) * sizeof(int), stream);
    prep_hist<<<PBLK_X + PBLK_W + PBLK_A + PBLK_H, 256, 0, stream>>>(
        x, Wt1, Wt2, Wa1, Wa2, dst, tix, xb, WT1, WT2, Wa1T, Wa2T, cnt);
    scan_all<<<NBLK1, 256, 0, stream>>>(cnt, bsum, chunkoff, done);
    scatter_edges<<<8 * 391, 256, 0, stream>>>(src, dst, tix, cnt, chunkoff, elist);

    fused_conv<false><<<CONV_GRID, 512, 0, stream>>>(
        xb, WT1, bt1, cnt, chunkoff, elist, h1b,
        nullptr, nullptr, nullptr, nullptr, nullptr, nullptr);
    fused_conv<true><<<CONV_GRID, 512, 0, stream>>>(
        h1b, WT2, bt2, cnt, chunkoff, elist, nullptr,
        Wa1T, ba1, Wa2T, ba2, h1b, out);
}

// Round 11
// 271.397 us; speedup vs baseline: 1.0623x; 1.0623x over previous
//
#include <hip/hip_runtime.h>

#define N_NODES 50000
#define C_FEAT  64
#define E_EDGES 800000
#define KEYS    400000          // dst*8 + t
#define NBLK1   391             // ceil(KEYS/1024)
#define DPB     16              // dsts per conv tile -> 16 MFMA rows
#define NTILES  (N_NODES / DPB) // 3125
#define PBLK_X  1563            // x->bf16 cvt blocks (8 elems/thread, last partial)
#define PBLK_W  128             // Wt transpose blocks
#define PBLK_A  64              // Wa1T/Wa2T transpose blocks (2 x 8192)
#define PBLK_H  391             // hist blocks: single pass, 2048 edges/block
#define DPART   6250            // dsts per XCD partition (scatter)

typedef __attribute__((ext_vector_type(8))) short short8;
typedef __attribute__((ext_vector_type(4))) float f32x4;

__device__ __forceinline__ float bf2f(unsigned short u) {
    union { unsigned int i; float f; } v; v.i = ((unsigned int)u) << 16; return v.f;
}
__device__ __forceinline__ unsigned short f2bf(float f) {
    union { float f; unsigned int i; } v; v.f = f;
    unsigned int r = v.i + 0x7fff + ((v.i >> 16) & 1);   // RNE
    return (unsigned short)(r >> 16);
}

// -------- prep (x->bf16, Wt->WT bf16, Wa->WaT bf16) + single-pass hist --------
__global__ __launch_bounds__(256) void prep_hist(const float* __restrict__ x,
                                                 const float* __restrict__ W1,
                                                 const float* __restrict__ W2,
                                                 const float* __restrict__ Wa1,
                                                 const float* __restrict__ Wa2,
                                                 const int* __restrict__ dst,
                                                 const int* __restrict__ tix,
                                                 unsigned short* __restrict__ xb,
                                                 unsigned short* __restrict__ WT1,
                                                 unsigned short* __restrict__ WT2,
                                                 unsigned short* __restrict__ Wa1T,
                                                 unsigned short* __restrict__ Wa2T,
                                                 int* __restrict__ cnt) {
    const int b = blockIdx.x;
    if (b < PBLK_X) {
        int base = (b * 256 + threadIdx.x) * 8;
        if (base < N_NODES * 64) {
            float4 a = *(const float4*)(x + base);
            float4 c = *(const float4*)(x + base + 4);
            short8 o;
            o[0] = (short)f2bf(a.x); o[1] = (short)f2bf(a.y);
            o[2] = (short)f2bf(a.z); o[3] = (short)f2bf(a.w);
            o[4] = (short)f2bf(c.x); o[5] = (short)f2bf(c.y);
            o[6] = (short)f2bf(c.z); o[7] = (short)f2bf(c.w);
            *(short8*)(xb + base) = o;
        }
    } else if (b < PBLK_X + PBLK_W) {
        int i = (b - PBLK_X) * 256 + threadIdx.x;      // 32768
        int n = i >> 9, k = i & 511;
        WT1[i] = f2bf(W1[k * 64 + n]);
        WT2[i] = f2bf(W2[k * 64 + n]);
    } else if (b < PBLK_X + PBLK_W + PBLK_A) {
        int i = (b - PBLK_X - PBLK_W) * 256 + threadIdx.x;   // 0..16383
        if (i < 8192) {                                // Wa1T[128][64] <- Wa1[64][128]
            int n = i >> 6, k = i & 63;
            Wa1T[i] = f2bf(Wa1[k * 128 + n]);
        } else {                                       // Wa2T[64][128] <- Wa2[128][64]
            int ii = i - 8192;
            int n = ii >> 7, k = ii & 127;
            Wa2T[ii] = f2bf(Wa2[k * 64 + n]);
        }
    } else {
        // single-pass hist: every edge visited once; atomics fire-and-forget
        int bb = b - PBLK_X - PBLK_W - PBLK_A;         // 0..390
        const int e0 = bb * 2048 + threadIdx.x * 8;
        if (e0 < E_EDGES) {                            // E%8==0 -> window fully in-bounds
            int4 d0 = *(const int4*)(dst + e0);
            int4 d1 = *(const int4*)(dst + e0 + 4);
            int4 t0 = *(const int4*)(tix + e0);
            int4 t1 = *(const int4*)(tix + e0 + 4);
            int dd[8] = {d0.x, d0.y, d0.z, d0.w, d1.x, d1.y, d1.z, d1.w};
            int tt[8] = {t0.x, t0.y, t0.z, t0.w, t1.x, t1.y, t1.z, t1.w};
            #pragma unroll
            for (int k = 0; k < 8; ++k)
                atomicAdd(&cnt[dd[k] * 8 + tt[k]], 1);
        }
    }
}

// -------- scan_all: per-chunk local scan; LAST block scans chunk totals --------
__global__ __launch_bounds__(256) void scan_all(int* __restrict__ cnt,
                                                int* __restrict__ bsum,
                                                int* __restrict__ chunkoff,
                                                int* __restrict__ done) {
    __shared__ int wsum[4];
    __shared__ int ticket;
    const int tid = threadIdx.x;
    const int lane = tid & 63;
    const int wave = tid >> 6;
    const int i4 = blockIdx.x * 256 + tid;
    int4 v = make_int4(0, 0, 0, 0);
    const bool ok = (i4 * 4 < KEYS);
    if (ok) v = ((const int4*)cnt)[i4];
    int s = v.x + v.y + v.z + v.w;
    int sc = s;
    #pragma unroll
    for (int d = 1; d < 64; d <<= 1) {
        int o = __shfl_up(sc, d, 64);
        if (lane >= d) sc += o;
    }
    if (lane == 63) wsum[wave] = sc;
    __syncthreads();
    int wbase = 0;
    #pragma unroll
    for (int w = 0; w < 4; ++w) wbase += (w < wave) ? wsum[w] : 0;
    int base = wbase + sc - s;
    int4 o;
    o.x = base;
    o.y = base + v.x;
    o.z = o.y + v.y;
    o.w = o.z + v.z;
    if (ok) ((int4*)cnt)[i4] = o;
    if (tid == 255) {
        bsum[blockIdx.x] = wbase + sc;
        __threadfence();
        ticket = atomicAdd(done, 1);
    }
    __syncthreads();
    if (ticket == NBLK1 - 1 && wave == 0) {
        int carry = 0;
        #pragma unroll
        for (int g = 0; g < (NBLK1 + 63) / 64; ++g) {
            int j = g * 64 + lane;
            int val = (j < NBLK1) ? atomicAdd(&bsum[j], 0) : 0;
            int scn = val;
            #pragma unroll
            for (int d = 1; d < 64; d <<= 1) {
                int oo = __shfl_up(scn, d, 64);
                if (lane >= d) scn += oo;
            }
            if (j < NBLK1) chunkoff[j] = carry + scn - val;
            carry += __shfl(scn, 63, 64);
        }
    }
}

// -------- XCD-partitioned scatter (8-pass, proven): elist word carries dlocal --------
__global__ __launch_bounds__(256) void scatter_edges(const int* __restrict__ src,
                                                     const int* __restrict__ dst,
                                                     const int* __restrict__ tix,
                                                     int* __restrict__ cursor,
                                                     const int* __restrict__ chunkoff,
                                                     int* __restrict__ elist) {
    const int g = blockIdx.x & 7;                    // partition (XCD-affine)
    const int lo = g * DPART;
    const int e0 = (blockIdx.x >> 3) * 2048 + threadIdx.x * 8;
    if (e0 < E_EDGES) {                              // E%8==0 -> window fully in-bounds
        int4 d0 = *(const int4*)(dst + e0);
        int4 d1 = *(const int4*)(dst + e0 + 4);
        int4 t0 = *(const int4*)(tix + e0);
        int4 t1 = *(const int4*)(tix + e0 + 4);
        int4 s0 = *(const int4*)(src + e0);
        int4 s1 = *(const int4*)(src + e0 + 4);
        int dd[8] = {d0.x, d0.y, d0.z, d0.w, d1.x, d1.y, d1.z, d1.w};
        int tt[8] = {t0.x, t0.y, t0.z, t0.w, t1.x, t1.y, t1.z, t1.w};
        int ss[8] = {s0.x, s0.y, s0.z, s0.w, s1.x, s1.y, s1.z, s1.w};
        #pragma unroll
        for (int k = 0; k < 8; ++k) {
            if ((unsigned)(dd[k] - lo) < (unsigned)DPART) {
                int key = dd[k] * 8 + tt[k];
                int pos = chunkoff[key >> 10] + atomicAdd(&cursor[key], 1);
                elist[pos] = ss[k] | (tt[k] << 16) | ((dd[k] & 15) << 19);
            }
        }
    }
}

// -------- fused conv: 256-thread blocks (4 waves), 8 blocks/CU, 1 merged 4-dst
// stream per wave, 16-deep, bf16 LDS tile, MFMA epilogue on ALL waves --------
// Finer blocks vs R9's 512: barriers cover 4 waves, 8 independent blocks/CU
// fill each other's stalls, epilogue has no idle waves, imbalance mult drops
// (max-of-4 Pois(64) ~1.14x vs max-of-8 Pois(32) ~1.25x). Inner loop = R9.
#define FLUSH(P, V)                                                                   \
    { int _k = (P) >> 16;                                                             \
      if (_k != cur) { scat[cur >> 3][(cur & 7) * 64 + c] = f2bf(acc);                \
                       acc = 0.f; cur = _k; }                                         \
      acc += (V); }

#define EDGE(K)                                                                       \
    int p##K = __builtin_amdgcn_readlane(pv, e + K);                                  \
    float v##K = bf2f(Xb[(size_t)(p##K & 0xffff) * 64 + c]);

template <bool ADV>
__global__ __launch_bounds__(256, 8) void fused_conv(const unsigned short* __restrict__ Xb,
                                                     const unsigned short* __restrict__ WT,
                                                     const float* __restrict__ bias,
                                                     const int* __restrict__ segend,   // local ends
                                                     const int* __restrict__ chunkoff,
                                                     const int* __restrict__ elist,
                                                     unsigned short* __restrict__ Hb,
                                                     const unsigned short* __restrict__ Wa1T,
                                                     const float* __restrict__ ba1,
                                                     const unsigned short* __restrict__ Wa2T,
                                                     const float* __restrict__ ba2,
                                                     const unsigned short* __restrict__ h1r,
                                                     float* __restrict__ outF) {
    __shared__ __attribute__((aligned(16))) unsigned short scat[DPB][520];
    // adv-phase aliases over the scat pool (used only after a barrier)
    unsigned short (*sH)[72]  = (unsigned short(*)[72])&scat[0][0];          // 2304 B
    unsigned short (*sT)[136] = (unsigned short(*)[136])((char*)scat + 4096); // 4352 B
    const int lane = threadIdx.x & 63;
    const int wave = threadIdx.x >> 6;               // 0..3
    const int c = lane;
    const int dbase = blockIdx.x * DPB;

    {   // zero own 4 rows
        short8 z = {};
        *(short8*)&scat[wave * 4 + 0][lane * 8] = z;
        *(short8*)&scat[wave * 4 + 1][lane * 8] = z;
        *(short8*)&scat[wave * 4 + 2][lane * 8] = z;
        *(short8*)&scat[wave * 4 + 3][lane * 8] = z;
    }

    // contiguous stream for dst quad {dbase+4w .. dbase+4w+3}
    const int dquad = dbase + wave * 4;
    const int k0 = dquad * 8;
    const int sbeg = (dquad == 0) ? 0 : chunkoff[(k0 - 1) >> 10] + segend[k0 - 1];
    const int send = chunkoff[(k0 + 31) >> 10] + segend[k0 + 31];
    int pv = (lane < send - sbeg) ? elist[sbeg + lane] : 0;

    {
        int i = sbeg;
        int cur = 0;
        float acc = 0.f;
        if (i < send) cur = __builtin_amdgcn_readlane(pv, 0) >> 16;
        while (i < send) {
            int cnt = send - i; cnt = (cnt > 64) ? 64 : cnt;
            int pvn = 0;
            if (i + 64 < send) pvn = (lane < send - i - 64) ? elist[i + 64 + lane] : 0;
            int e = 0;
            for (; e + 15 < cnt; e += 16) {          // 16 gathers in flight
                EDGE(0)  EDGE(1)  EDGE(2)  EDGE(3)
                EDGE(4)  EDGE(5)  EDGE(6)  EDGE(7)
                EDGE(8)  EDGE(9)  EDGE(10) EDGE(11)
                EDGE(12) EDGE(13) EDGE(14) EDGE(15)
                FLUSH(p0, v0)   FLUSH(p1, v1)   FLUSH(p2, v2)   FLUSH(p3, v3)
                FLUSH(p4, v4)   FLUSH(p5, v5)   FLUSH(p6, v6)   FLUSH(p7, v7)
                FLUSH(p8, v8)   FLUSH(p9, v9)   FLUSH(p10, v10) FLUSH(p11, v11)
                FLUSH(p12, v12) FLUSH(p13, v13) FLUSH(p14, v14) FLUSH(p15, v15)
            }
            if (e + 7 < cnt) {                       // tail tier 8
                EDGE(0) EDGE(1) EDGE(2) EDGE(3) EDGE(4) EDGE(5) EDGE(6) EDGE(7)
                FLUSH(p0, v0) FLUSH(p1, v1) FLUSH(p2, v2) FLUSH(p3, v3)
                FLUSH(p4, v4) FLUSH(p5, v5) FLUSH(p6, v6) FLUSH(p7, v7)
                e += 8;
            }
            if (e + 3 < cnt) {                       // tail tier 4
                EDGE(0) EDGE(1) EDGE(2) EDGE(3)
                FLUSH(p0, v0) FLUSH(p1, v1) FLUSH(p2, v2) FLUSH(p3, v3)
                e += 4;
            }
            if (e + 1 < cnt) {                       // tail tier 2
                EDGE(0) EDGE(1)
                FLUSH(p0, v0) FLUSH(p1, v1)
                e += 2;
            }
            if (e < cnt) {                           // tail tier 1
                EDGE(0)
                FLUSH(p0, v0)
            }
            i += 64;
            pv = pvn;
        }
        if (sbeg < send)
            scat[cur >> 3][(cur & 7) * 64 + c] = f2bf(acc);
    }
    __syncthreads();

    // MFMA [16,512]@[512,64] on all 4 waves; C/D col=lane&15, row=quad*4+r (m89/m91)
    const int m = lane & 15;
    const int quad = lane >> 4;
    f32x4 acc4 = {0.f, 0.f, 0.f, 0.f};
    {
        const int n0 = wave * 16;
        const unsigned short* wrow = WT + (size_t)(n0 + m) * 512;
        #pragma unroll
        for (int kc = 0; kc < 16; ++kc) {
            short8 af = *(const short8*)&scat[m][kc * 32 + quad * 8];
            short8 bf = *(const short8*)(wrow + kc * 32 + quad * 8);
            acc4 = __builtin_amdgcn_mfma_f32_16x16x32_bf16(af, bf, acc4, 0, 0, 0);
        }
    }

    if (!ADV) {
        const int col = wave * 16 + m;
        const float bcol = bias[col];
        #pragma unroll
        for (int r = 0; r < 4; ++r) {
            int node = dbase + quad * 4 + r;
            Hb[(size_t)node * 64 + col] = f2bf(fmaxf(acc4[r] + bcol, 0.f));
        }
    } else {
        // ---- fused adversary MLP on this tile's 16 nodes ----
        __syncthreads();                     // all scat MFMA reads complete
        {                                    // h2 (relu'd, bf16) -> sH
            const int col = wave * 16 + m;
            const float bcol = bias[col];
            #pragma unroll
            for (int r = 0; r < 4; ++r)
                sH[quad * 4 + r][col] = f2bf(fmaxf(acc4[r] + bcol, 0.f));
        }
        __syncthreads();
        {   // GEMM1: [16,64]@[64,128]; 4 waves x two 16-col tiles
            #pragma unroll
            for (int ct = 0; ct < 2; ++ct) {
                f32x4 a1 = {0.f, 0.f, 0.f, 0.f};
                const int col = (wave * 2 + ct) * 16 + m;
                #pragma unroll
                for (int kc = 0; kc < 2; ++kc) {
                    short8 af = *(const short8*)&sH[m][kc * 32 + quad * 8];
                    short8 bf = *(const short8*)(Wa1T + (size_t)col * 64 + kc * 32 + quad * 8);
                    a1 = __builtin_amdgcn_mfma_f32_16x16x32_bf16(af, bf, a1, 0, 0, 0);
                }
                const float b1 = ba1[col];
                #pragma unroll
                for (int r = 0; r < 4; ++r)
                    sT[quad * 4 + r][col] = f2bf(fmaxf(a1[r] + b1, 0.f));
            }
        }
        __syncthreads();
        {   // GEMM2: [16,128]@[128,64]; 4 waves x one 16-col tile; + ba2 + h1
            f32x4 a2 = {0.f, 0.f, 0.f, 0.f};
            const int col = wave * 16 + m;
            #pragma unroll
            for (int kc = 0; kc < 4; ++kc) {
                short8 af = *(const short8*)&sT[m][kc * 32 + quad * 8];
                short8 bf = *(const short8*)(Wa2T + (size_t)col * 128 + kc * 32 + quad * 8);
                a2 = __builtin_amdgcn_mfma_f32_16x16x32_bf16(af, bf, a2, 0, 0, 0);
            }
            const float b2 = ba2[col];
            #pragma unroll
            for (int r = 0; r < 4; ++r) {
                int node = dbase + quad * 4 + r;
                outF[(size_t)node * 64 + col] =
                    a2[r] + b2 + bf2f(h1r[(size_t)node * 64 + col]);
            }
        }
    }
}

extern "C" void kernel_launch(void* const* d_in, const int* in_sizes, int n_in,
                              void* d_out, int out_size, void* d_ws, size_t ws_size,
                              hipStream_t stream) {
    const float* x   = (const float*)d_in[0];
    const int*   ei  = (const int*)d_in[1];
    const int*   tix = (const int*)d_in[2];
    const float* Wt1 = (const float*)d_in[3];
    const float* bt1 = (const float*)d_in[4];
    const float* Wt2 = (const float*)d_in[5];
    const float* bt2 = (const float*)d_in[6];
    const float* Wa1 = (const float*)d_in[7];
    const float* ba1 = (const float*)d_in[8];
    const float* Wa2 = (const float*)d_in[9];
    const float* ba2 = (const float*)d_in[10];
    float* out = (float*)d_out;

    const int* src = ei;
    const int* dst = ei + E_EDGES;

    // workspace (~25 MB)
    unsigned short* xb   = (unsigned short*)d_ws;          // [N,64] bf16
    unsigned short* h1b  = xb + (size_t)N_NODES * 64;      // [N,64] bf16
    unsigned short* h2b  = h1b + (size_t)N_NODES * 64;     // [N,64] bf16 (unused now)
    unsigned short* WT1  = h2b + (size_t)N_NODES * 64;     // [64,512] bf16
    unsigned short* WT2  = WT1 + 64 * 512;
    unsigned short* Wa1T = WT2 + 64 * 512;                 // [128,64] bf16
    unsigned short* Wa2T = Wa1T + 8192;                    // [64,128] bf16
    int* cnt      = (int*)(Wa2T + 8192);                   // KEYS
    int* bsum     = cnt + KEYS;                            // 512
    int* chunkoff = bsum + 512;                            // 512
    int* done     = chunkoff + 512;                        // 64 (1 used)
    int* elist    = done + 64;                             // E packed (src | t<<16 | dl<<19)

    hipMemsetAsync(cnt, 0, (KEYS + 512 + 512 + 64) * sizeof(int), stream);
    prep_hist<<<PBLK_X + PBLK_W + PBLK_A + PBLK_H, 256, 0, stream>>>(
        x, Wt1, Wt2, Wa1, Wa2, dst, tix, xb, WT1, WT2, Wa1T, Wa2T, cnt);
    scan_all<<<NBLK1, 256, 0, stream>>>(cnt, bsum, chunkoff, done);
    scatter_edges<<<8 * 391, 256, 0, stream>>>(src, dst, tix, cnt, chunkoff, elist);

    fused_conv<false><<<NTILES, 256, 0, stream>>>(
        xb, WT1, bt1, cnt, chunkoff, elist, h1b,
        nullptr, nullptr, nullptr, nullptr, nullptr, nullptr);
    fused_conv<true><<<NTILES, 256, 0, stream>>>(
        h1b, WT2, bt2, cnt, chunkoff, elist, nullptr,
        Wa1T, ba1, Wa2T, ba2, h1b, out);
}

// Round 12
// 253.579 us; speedup vs baseline: 1.1369x; 1.0703x over previous
//
#include <hip/hip_runtime.h>

#define N_NODES 50000
#define C_FEAT  64
#define E_EDGES 800000
#define KEYS    400000          // dst*8 + t
#define NBLK1   391             // ceil(KEYS/1024)
#define DPB     16              // dsts per conv tile -> 16 MFMA rows
#define NTILES  (N_NODES / DPB) // 3125
#define PBLK_X  1563            // x->bf16 cvt blocks (8 elems/thread, last partial)
#define PBLK_W  128             // Wt transpose blocks
#define PBLK_A  64              // Wa1T/Wa2T transpose blocks (2 x 8192)
#define PBLK_H  391             // hist+rank blocks: single pass, 2048 edges/block

typedef __attribute__((ext_vector_type(8))) short short8;
typedef __attribute__((ext_vector_type(4))) float f32x4;

__device__ __forceinline__ float bf2f(unsigned short u) {
    union { unsigned int i; float f; } v; v.i = ((unsigned int)u) << 16; return v.f;
}
__device__ __forceinline__ unsigned short f2bf(float f) {
    union { float f; unsigned int i; } v; v.f = f;
    unsigned int r = v.i + 0x7fff + ((v.i >> 16) & 1);   // RNE
    return (unsigned short)(r >> 16);
}

// -------- prep (x->bf16, Wt->WT bf16, Wa->WaT bf16) + hist WITH rank records --------
// hist atomicAdd returns within-key rank for free; rec = (payload, key|rank<<19).
// The 8 atomics per thread are independent (returns feed only rec stores) ->
// they pipeline; no dependent chain (R4 lesson respected).
__global__ __launch_bounds__(256) void prep_hist(const float* __restrict__ x,
                                                 const float* __restrict__ W1,
                                                 const float* __restrict__ W2,
                                                 const float* __restrict__ Wa1,
                                                 const float* __restrict__ Wa2,
                                                 const int* __restrict__ src,
                                                 const int* __restrict__ dst,
                                                 const int* __restrict__ tix,
                                                 unsigned short* __restrict__ xb,
                                                 unsigned short* __restrict__ WT1,
                                                 unsigned short* __restrict__ WT2,
                                                 unsigned short* __restrict__ Wa1T,
                                                 unsigned short* __restrict__ Wa2T,
                                                 int* __restrict__ cnt,
                                                 int2* __restrict__ rec) {
    const int b = blockIdx.x;
    if (b < PBLK_X) {
        int base = (b * 256 + threadIdx.x) * 8;
        if (base < N_NODES * 64) {
            float4 a = *(const float4*)(x + base);
            float4 c = *(const float4*)(x + base + 4);
            short8 o;
            o[0] = (short)f2bf(a.x); o[1] = (short)f2bf(a.y);
            o[2] = (short)f2bf(a.z); o[3] = (short)f2bf(a.w);
            o[4] = (short)f2bf(c.x); o[5] = (short)f2bf(c.y);
            o[6] = (short)f2bf(c.z); o[7] = (short)f2bf(c.w);
            *(short8*)(xb + base) = o;
        }
    } else if (b < PBLK_X + PBLK_W) {
        int i = (b - PBLK_X) * 256 + threadIdx.x;      // 32768
        int n = i >> 9, k = i & 511;
        WT1[i] = f2bf(W1[k * 64 + n]);
        WT2[i] = f2bf(W2[k * 64 + n]);
    } else if (b < PBLK_X + PBLK_W + PBLK_A) {
        int i = (b - PBLK_X - PBLK_W) * 256 + threadIdx.x;   // 0..16383
        if (i < 8192) {                                // Wa1T[128][64] <- Wa1[64][128]
            int n = i >> 6, k = i & 63;
            Wa1T[i] = f2bf(Wa1[k * 128 + n]);
        } else {                                       // Wa2T[64][128] <- Wa2[128][64]
            int ii = i - 8192;
            int n = ii >> 7, k = ii & 127;
            Wa2T[ii] = f2bf(Wa2[k * 64 + n]);
        }
    } else {
        // hist + rank: every edge visited once
        int bb = b - PBLK_X - PBLK_W - PBLK_A;         // 0..390
        const int e0 = bb * 2048 + threadIdx.x * 8;
        if (e0 < E_EDGES) {                            // E%8==0 -> window fully in-bounds
            int4 d0 = *(const int4*)(dst + e0);
            int4 d1 = *(const int4*)(dst + e0 + 4);
            int4 t0 = *(const int4*)(tix + e0);
            int4 t1 = *(const int4*)(tix + e0 + 4);
            int4 s0 = *(const int4*)(src + e0);
            int4 s1 = *(const int4*)(src + e0 + 4);
            int dd[8] = {d0.x, d0.y, d0.z, d0.w, d1.x, d1.y, d1.z, d1.w};
            int tt[8] = {t0.x, t0.y, t0.z, t0.w, t1.x, t1.y, t1.z, t1.w};
            int ss[8] = {s0.x, s0.y, s0.z, s0.w, s1.x, s1.y, s1.z, s1.w};
            int rk[8];
            #pragma unroll
            for (int k = 0; k < 8; ++k)                // 8 independent atomics in flight
                rk[k] = atomicAdd(&cnt[dd[k] * 8 + tt[k]], 1);
            #pragma unroll
            for (int k = 0; k < 8; ++k)                // coalesced 64B/thread rec store
                rec[e0 + k] = make_int2(ss[k] | (tt[k] << 16) | ((dd[k] & 15) << 19),
                                        (dd[k] * 8 + tt[k]) | (rk[k] << 19));
        }
    }
}

// -------- scan_all: per-chunk local scan; LAST block scans chunk totals --------
__global__ __launch_bounds__(256) void scan_all(int* __restrict__ cnt,
                                                int* __restrict__ bsum,
                                                int* __restrict__ chunkoff,
                                                int* __restrict__ done) {
    __shared__ int wsum[4];
    __shared__ int ticket;
    const int tid = threadIdx.x;
    const int lane = tid & 63;
    const int wave = tid >> 6;
    const int i4 = blockIdx.x * 256 + tid;
    int4 v = make_int4(0, 0, 0, 0);
    const bool ok = (i4 * 4 < KEYS);
    if (ok) v = ((const int4*)cnt)[i4];
    int s = v.x + v.y + v.z + v.w;
    int sc = s;
    #pragma unroll
    for (int d = 1; d < 64; d <<= 1) {
        int o = __shfl_up(sc, d, 64);
        if (lane >= d) sc += o;
    }
    if (lane == 63) wsum[wave] = sc;
    __syncthreads();
    int wbase = 0;
    #pragma unroll
    for (int w = 0; w < 4; ++w) wbase += (w < wave) ? wsum[w] : 0;
    int base = wbase + sc - s;
    int4 o;
    o.x = base;
    o.y = base + v.x;
    o.z = o.y + v.y;
    o.w = o.z + v.z;
    if (ok) ((int4*)cnt)[i4] = o;
    if (tid == 255) {
        bsum[blockIdx.x] = wbase + sc;
        __threadfence();
        ticket = atomicAdd(done, 1);
    }
    __syncthreads();
    if (ticket == NBLK1 - 1 && wave == 0) {
        int carry = 0;
        #pragma unroll
        for (int g = 0; g < (NBLK1 + 63) / 64; ++g) {
            int j = g * 64 + lane;
            int val = (j < NBLK1) ? atomicAdd(&bsum[j], 0) : 0;
            int scn = val;
            #pragma unroll
            for (int d = 1; d < 64; d <<= 1) {
                int oo = __shfl_up(scn, d, 64);
                if (lane >= d) scn += oo;
            }
            if (j < NBLK1) chunkoff[j] = carry + scn - val;
            carry += __shfl(scn, 63, 64);
        }
    }
}

// -------- rank-based scatter: NO atomics, 1 edge per 2 lanes, fire-and-forget --------
// pos = chunkoff[key>>10] + cnt[key] + rank. 400k threads, fully independent.
__global__ __launch_bounds__(256) void scatter_rank(const int2* __restrict__ rec,
                                                    const int* __restrict__ cnt,
                                                    const int* __restrict__ chunkoff,
                                                    int* __restrict__ elist) {
    const int i = (blockIdx.x * 256 + threadIdx.x) * 2;
    if (i < E_EDGES) {                               // E%2==0 -> pair in-bounds
        int4 r = *(const int4*)(rec + i);            // recs i, i+1
        int key0 = r.y & 0x7ffff, rank0 = (int)((unsigned)r.y >> 19);
        int key1 = r.w & 0x7ffff, rank1 = (int)((unsigned)r.w >> 19);
        elist[chunkoff[key0 >> 10] + cnt[key0] + rank0] = r.x;
        elist[chunkoff[key1 >> 10] + cnt[key1] + rank1] = r.z;
    }
}

// -------- fused conv: 256-thread blocks (4 waves), merged 4-dst stream/wave,
// 16-deep, bf16 LDS tile, MFMA+ADV epilogue on ALL waves (R11 structure) --------
// cstart = cnt after scan (START offsets, never mutated): seg bounds are
// keystart[k0] .. keystart[k0+32]; no tile-0 special case.
#define FLUSH(P, V)                                                                   \
    { int _k = (P) >> 16;                                                             \
      if (_k != cur) { scat[cur >> 3][(cur & 7) * 64 + c] = f2bf(acc);                \
                       acc = 0.f; cur = _k; }                                         \
      acc += (V); }

#define EDGE(K)                                                                       \
    int p##K = __builtin_amdgcn_readlane(pv, e + K);                                  \
    float v##K = bf2f(Xb[(size_t)(p##K & 0xffff) * 64 + c]);

template <bool ADV>
__global__ __launch_bounds__(256, 8) void fused_conv(const unsigned short* __restrict__ Xb,
                                                     const unsigned short* __restrict__ WT,
                                                     const float* __restrict__ bias,
                                                     const int* __restrict__ cstart,   // start offsets
                                                     const int* __restrict__ chunkoff,
                                                     const int* __restrict__ elist,
                                                     unsigned short* __restrict__ Hb,
                                                     const unsigned short* __restrict__ Wa1T,
                                                     const float* __restrict__ ba1,
                                                     const unsigned short* __restrict__ Wa2T,
                                                     const float* __restrict__ ba2,
                                                     const unsigned short* __restrict__ h1r,
                                                     float* __restrict__ outF) {
    __shared__ __attribute__((aligned(16))) unsigned short scat[DPB][520];
    // adv-phase aliases over the scat pool (used only after a barrier)
    unsigned short (*sH)[72]  = (unsigned short(*)[72])&scat[0][0];          // 2304 B
    unsigned short (*sT)[136] = (unsigned short(*)[136])((char*)scat + 4096); // 4352 B
    const int lane = threadIdx.x & 63;
    const int wave = threadIdx.x >> 6;               // 0..3
    const int c = lane;
    const int dbase = blockIdx.x * DPB;

    {   // zero own 4 rows
        short8 z = {};
        *(short8*)&scat[wave * 4 + 0][lane * 8] = z;
        *(short8*)&scat[wave * 4 + 1][lane * 8] = z;
        *(short8*)&scat[wave * 4 + 2][lane * 8] = z;
        *(short8*)&scat[wave * 4 + 3][lane * 8] = z;
    }

    // contiguous stream for dst quad {dbase+4w .. dbase+4w+3}
    const int k0 = (dbase + wave * 4) * 8;
    const int k1 = k0 + 32;
    const int sbeg = chunkoff[k0 >> 10] + cstart[k0];
    const int send = (k1 >= KEYS) ? E_EDGES : chunkoff[k1 >> 10] + cstart[k1];
    int pv = (lane < send - sbeg) ? elist[sbeg + lane] : 0;

    {
        int i = sbeg;
        int cur = 0;
        float acc = 0.f;
        if (i < send) cur = __builtin_amdgcn_readlane(pv, 0) >> 16;
        while (i < send) {
            int cnt = send - i; cnt = (cnt > 64) ? 64 : cnt;
            int pvn = 0;
            if (i + 64 < send) pvn = (lane < send - i - 64) ? elist[i + 64 + lane] : 0;
            int e = 0;
            for (; e + 15 < cnt; e += 16) {          // 16 gathers in flight
                EDGE(0)  EDGE(1)  EDGE(2)  EDGE(3)
                EDGE(4)  EDGE(5)  EDGE(6)  EDGE(7)
                EDGE(8)  EDGE(9)  EDGE(10) EDGE(11)
                EDGE(12) EDGE(13) EDGE(14) EDGE(15)
                FLUSH(p0, v0)   FLUSH(p1, v1)   FLUSH(p2, v2)   FLUSH(p3, v3)
                FLUSH(p4, v4)   FLUSH(p5, v5)   FLUSH(p6, v6)   FLUSH(p7, v7)
                FLUSH(p8, v8)   FLUSH(p9, v9)   FLUSH(p10, v10) FLUSH(p11, v11)
                FLUSH(p12, v12) FLUSH(p13, v13) FLUSH(p14, v14) FLUSH(p15, v15)
            }
            if (e + 7 < cnt) {                       // tail tier 8
                EDGE(0) EDGE(1) EDGE(2) EDGE(3) EDGE(4) EDGE(5) EDGE(6) EDGE(7)
                FLUSH(p0, v0) FLUSH(p1, v1) FLUSH(p2, v2) FLUSH(p3, v3)
                FLUSH(p4, v4) FLUSH(p5, v5) FLUSH(p6, v6) FLUSH(p7, v7)
                e += 8;
            }
            if (e + 3 < cnt) {                       // tail tier 4
                EDGE(0) EDGE(1) EDGE(2) EDGE(3)
                FLUSH(p0, v0) FLUSH(p1, v1) FLUSH(p2, v2) FLUSH(p3, v3)
                e += 4;
            }
            if (e + 1 < cnt) {                       // tail tier 2
                EDGE(0) EDGE(1)
                FLUSH(p0, v0) FLUSH(p1, v1)
                e += 2;
            }
            if (e < cnt) {                           // tail tier 1
                EDGE(0)
                FLUSH(p0, v0)
            }
            i += 64;
            pv = pvn;
        }
        if (sbeg < send)
            scat[cur >> 3][(cur & 7) * 64 + c] = f2bf(acc);
    }
    __syncthreads();

    // MFMA [16,512]@[512,64] on all 4 waves; C/D col=lane&15, row=quad*4+r (m89/m91)
    const int m = lane & 15;
    const int quad = lane >> 4;
    f32x4 acc4 = {0.f, 0.f, 0.f, 0.f};
    {
        const int n0 = wave * 16;
        const unsigned short* wrow = WT + (size_t)(n0 + m) * 512;
        #pragma unroll
        for (int kc = 0; kc < 16; ++kc) {
            short8 af = *(const short8*)&scat[m][kc * 32 + quad * 8];
            short8 bf = *(const short8*)(wrow + kc * 32 + quad * 8);
            acc4 = __builtin_amdgcn_mfma_f32_16x16x32_bf16(af, bf, acc4, 0, 0, 0);
        }
    }

    if (!ADV) {
        const int col = wave * 16 + m;
        const float bcol = bias[col];
        #pragma unroll
        for (int r = 0; r < 4; ++r) {
            int node = dbase + quad * 4 + r;
            Hb[(size_t)node * 64 + col] = f2bf(fmaxf(acc4[r] + bcol, 0.f));
        }
    } else {
        // ---- fused adversary MLP on this tile's 16 nodes ----
        __syncthreads();                     // all scat MFMA reads complete
        {                                    // h2 (relu'd, bf16) -> sH
            const int col = wave * 16 + m;
            const float bcol = bias[col];
            #pragma unroll
            for (int r = 0; r < 4; ++r)
                sH[quad * 4 + r][col] = f2bf(fmaxf(acc4[r] + bcol, 0.f));
        }
        __syncthreads();
        {   // GEMM1: [16,64]@[64,128]; 4 waves x two 16-col tiles
            #pragma unroll
            for (int ct = 0; ct < 2; ++ct) {
                f32x4 a1 = {0.f, 0.f, 0.f, 0.f};
                const int col = (wave * 2 + ct) * 16 + m;
                #pragma unroll
                for (int kc = 0; kc < 2; ++kc) {
                    short8 af = *(const short8*)&sH[m][kc * 32 + quad * 8];
                    short8 bf = *(const short8*)(Wa1T + (size_t)col * 64 + kc * 32 + quad * 8);
                    a1 = __builtin_amdgcn_mfma_f32_16x16x32_bf16(af, bf, a1, 0, 0, 0);
                }
                const float b1 = ba1[col];
                #pragma unroll
                for (int r = 0; r < 4; ++r)
                    sT[quad * 4 + r][col] = f2bf(fmaxf(a1[r] + b1, 0.f));
            }
        }
        __syncthreads();
        {   // GEMM2: [16,128]@[128,64]; 4 waves x one 16-col tile; + ba2 + h1
            f32x4 a2 = {0.f, 0.f, 0.f, 0.f};
            const int col = wave * 16 + m;
            #pragma unroll
            for (int kc = 0; kc < 4; ++kc) {
                short8 af = *(const short8*)&sT[m][kc * 32 + quad * 8];
                short8 bf = *(const short8*)(Wa2T + (size_t)col * 128 + kc * 32 + quad * 8);
                a2 = __builtin_amdgcn_mfma_f32_16x16x32_bf16(af, bf, a2, 0, 0, 0);
            }
            const float b2 = ba2[col];
            #pragma unroll
            for (int r = 0; r < 4; ++r) {
                int node = dbase + quad * 4 + r;
                outF[(size_t)node * 64 + col] =
                    a2[r] + b2 + bf2f(h1r[(size_t)node * 64 + col]);
            }
        }
    }
}

extern "C" void kernel_launch(void* const* d_in, const int* in_sizes, int n_in,
                              void* d_out, int out_size, void* d_ws, size_t ws_size,
                              hipStream_t stream) {
    const float* x   = (const float*)d_in[0];
    const int*   ei  = (const int*)d_in[1];
    const int*   tix = (const int*)d_in[2];
    const float* Wt1 = (const float*)d_in[3];
    const float* bt1 = (const float*)d_in[4];
    const float* Wt2 = (const float*)d_in[5];
    const float* bt2 = (const float*)d_in[6];
    const float* Wa1 = (const float*)d_in[7];
    const float* ba1 = (const float*)d_in[8];
    const float* Wa2 = (const float*)d_in[9];
    const float* ba2 = (const float*)d_in[10];
    float* out = (float*)d_out;

    const int* src = ei;
    const int* dst = ei + E_EDGES;

    // workspace (~32 MB)
    unsigned short* xb   = (unsigned short*)d_ws;          // [N,64] bf16
    unsigned short* h1b  = xb + (size_t)N_NODES * 64;      // [N,64] bf16
    unsigned short* h2b  = h1b + (size_t)N_NODES * 64;     // [N,64] bf16 (unused)
    unsigned short* WT1  = h2b + (size_t)N_NODES * 64;     // [64,512] bf16
    unsigned short* WT2  = WT1 + 64 * 512;
    unsigned short* Wa1T = WT2 + 64 * 512;                 // [128,64] bf16
    unsigned short* Wa2T = Wa1T + 8192;                    // [64,128] bf16
    int* cnt      = (int*)(Wa2T + 8192);                   // KEYS
    int* bsum     = cnt + KEYS;                            // 512
    int* chunkoff = bsum + 512;                            // 512
    int* done     = chunkoff + 512;                        // 64 (1 used)
    int* elist    = done + 64;                             // E packed (src | t<<16 | dl<<19)
    int2* rec     = (int2*)(elist + E_EDGES);              // E records (payload, key|rank<<19)

    hipMemsetAsync(cnt, 0, (KEYS + 512 + 512 + 64) * sizeof(int), stream);
    prep_hist<<<PBLK_X + PBLK_W + PBLK_A + PBLK_H, 256, 0, stream>>>(
        x, Wt1, Wt2, Wa1, Wa2, src, dst, tix, xb, WT1, WT2, Wa1T, Wa2T, cnt, rec);
    scan_all<<<NBLK1, 256, 0, stream>>>(cnt, bsum, chunkoff, done);
    scatter_rank<<<(E_EDGES / 2 + 255) / 256, 256, 0, stream>>>(rec, cnt, chunkoff, elist);

    fused_conv<false><<<NTILES, 256, 0, stream>>>(
        xb, WT1, bt1, cnt, chunkoff, elist, h1b,
        nullptr, nullptr, nullptr, nullptr, nullptr, nullptr);
    fused_conv<true><<<NTILES, 256, 0, stream>>>(
        h1b, WT2, bt2, cnt, chunkoff, elist, nullptr,
        Wa1T, ba1, Wa2T, ba2, h1b, out);
}

// Round 13
// 245.139 us; speedup vs baseline: 1.1761x; 1.0344x over previous
//
#include <hip/hip_runtime.h>

#define N_NODES 50000
#define C_FEAT  64
#define E_EDGES 800000
#define KEYS    400000          // dst*8 + t
#define NBLK1   391             // ceil(KEYS/1024)
#define DPB     16              // dsts per conv tile -> 16 MFMA rows
#define NTILES  (N_NODES / DPB) // 3125
#define PBLK_X  1563            // x->bf16 cvt blocks (8 elems/thread, last partial)
#define PBLK_W  128             // Wt transpose blocks
#define PBLK_A  64              // Wa1T/Wa2T transpose blocks (2 x 8192)
#define PBLK_H  782             // hist+rank blocks: 4 edges/thread (1024/block)

typedef __attribute__((ext_vector_type(8))) short short8;
typedef __attribute__((ext_vector_type(4))) float f32x4;

__device__ __forceinline__ float bf2f(unsigned short u) {
    union { unsigned int i; float f; } v; v.i = ((unsigned int)u) << 16; return v.f;
}
__device__ __forceinline__ unsigned short f2bf(float f) {
    union { float f; unsigned int i; } v; v.f = f;
    unsigned int r = v.i + 0x7fff + ((v.i >> 16) & 1);   // RNE
    return (unsigned short)(r >> 16);
}

// -------- prep (x->bf16, Wt->WT bf16, Wa->WaT bf16) + hist WITH rank records --------
// hist atomicAdd returns within-key rank for free; rec = (payload, key|rank<<19).
// 4 edges/thread (R12 was 8): shorter independent atomic bursts, 2x TLP.
__global__ __launch_bounds__(256) void prep_hist(const float* __restrict__ x,
                                                 const float* __restrict__ W1,
                                                 const float* __restrict__ W2,
                                                 const float* __restrict__ Wa1,
                                                 const float* __restrict__ Wa2,
                                                 const int* __restrict__ src,
                                                 const int* __restrict__ dst,
                                                 const int* __restrict__ tix,
                                                 unsigned short* __restrict__ xb,
                                                 unsigned short* __restrict__ WT1,
                                                 unsigned short* __restrict__ WT2,
                                                 unsigned short* __restrict__ Wa1T,
                                                 unsigned short* __restrict__ Wa2T,
                                                 int* __restrict__ cnt,
                                                 int2* __restrict__ rec) {
    const int b = blockIdx.x;
    if (b < PBLK_X) {
        int base = (b * 256 + threadIdx.x) * 8;
        if (base < N_NODES * 64) {
            float4 a = *(const float4*)(x + base);
            float4 c = *(const float4*)(x + base + 4);
            short8 o;
            o[0] = (short)f2bf(a.x); o[1] = (short)f2bf(a.y);
            o[2] = (short)f2bf(a.z); o[3] = (short)f2bf(a.w);
            o[4] = (short)f2bf(c.x); o[5] = (short)f2bf(c.y);
            o[6] = (short)f2bf(c.z); o[7] = (short)f2bf(c.w);
            *(short8*)(xb + base) = o;
        }
    } else if (b < PBLK_X + PBLK_W) {
        int i = (b - PBLK_X) * 256 + threadIdx.x;      // 32768
        int n = i >> 9, k = i & 511;
        WT1[i] = f2bf(W1[k * 64 + n]);
        WT2[i] = f2bf(W2[k * 64 + n]);
    } else if (b < PBLK_X + PBLK_W + PBLK_A) {
        int i = (b - PBLK_X - PBLK_W) * 256 + threadIdx.x;   // 0..16383
        if (i < 8192) {                                // Wa1T[128][64] <- Wa1[64][128]
            int n = i >> 6, k = i & 63;
            Wa1T[i] = f2bf(Wa1[k * 128 + n]);
        } else {                                       // Wa2T[64][128] <- Wa2[128][64]
            int ii = i - 8192;
            int n = ii >> 7, k = ii & 127;
            Wa2T[ii] = f2bf(Wa2[k * 64 + n]);
        }
    } else {
        // hist + rank: every edge visited once, 4 edges/thread
        int bb = b - PBLK_X - PBLK_W - PBLK_A;         // 0..781
        const int e0 = bb * 1024 + threadIdx.x * 4;
        if (e0 < E_EDGES) {                            // E%4==0 -> window fully in-bounds
            int4 d = *(const int4*)(dst + e0);
            int4 t = *(const int4*)(tix + e0);
            int4 s = *(const int4*)(src + e0);
            int dd[4] = {d.x, d.y, d.z, d.w};
            int tt[4] = {t.x, t.y, t.z, t.w};
            int ss[4] = {s.x, s.y, s.z, s.w};
            int rk[4];
            #pragma unroll
            for (int k = 0; k < 4; ++k)                // 4 independent atomics in flight
                rk[k] = atomicAdd(&cnt[dd[k] * 8 + tt[k]], 1);
            #pragma unroll
            for (int k = 0; k < 4; ++k)                // coalesced 32B/thread rec store
                rec[e0 + k] = make_int2(ss[k] | (tt[k] << 16) | ((dd[k] & 15) << 19),
                                        (dd[k] * 8 + tt[k]) | (rk[k] << 19));
        }
    }
}

// -------- scan_all: per-chunk local scan; LAST block scans chunk totals --------
__global__ __launch_bounds__(256) void scan_all(int* __restrict__ cnt,
                                                int* __restrict__ bsum,
                                                int* __restrict__ chunkoff,
                                                int* __restrict__ done) {
    __shared__ int wsum[4];
    __shared__ int ticket;
    const int tid = threadIdx.x;
    const int lane = tid & 63;
    const int wave = tid >> 6;
    const int i4 = blockIdx.x * 256 + tid;
    int4 v = make_int4(0, 0, 0, 0);
    const bool ok = (i4 * 4 < KEYS);
    if (ok) v = ((const int4*)cnt)[i4];
    int s = v.x + v.y + v.z + v.w;
    int sc = s;
    #pragma unroll
    for (int d = 1; d < 64; d <<= 1) {
        int o = __shfl_up(sc, d, 64);
        if (lane >= d) sc += o;
    }
    if (lane == 63) wsum[wave] = sc;
    __syncthreads();
    int wbase = 0;
    #pragma unroll
    for (int w = 0; w < 4; ++w) wbase += (w < wave) ? wsum[w] : 0;
    int base = wbase + sc - s;
    int4 o;
    o.x = base;
    o.y = base + v.x;
    o.z = o.y + v.y;
    o.w = o.z + v.z;
    if (ok) ((int4*)cnt)[i4] = o;
    if (tid == 255) {
        bsum[blockIdx.x] = wbase + sc;
        __threadfence();
        ticket = atomicAdd(done, 1);
    }
    __syncthreads();
    if (ticket == NBLK1 - 1 && wave == 0) {
        int carry = 0;
        #pragma unroll
        for (int g = 0; g < (NBLK1 + 63) / 64; ++g) {
            int j = g * 64 + lane;
            int val = (j < NBLK1) ? atomicAdd(&bsum[j], 0) : 0;
            int scn = val;
            #pragma unroll
            for (int d = 1; d < 64; d <<= 1) {
                int oo = __shfl_up(scn, d, 64);
                if (lane >= d) scn += oo;
            }
            if (j < NBLK1) chunkoff[j] = carry + scn - val;
            carry += __shfl(scn, 63, 64);
        }
    }
}

// -------- rank-based scatter: NO atomics, fire-and-forget --------
// pos = chunkoff[key>>10] + cnt[key] + rank. 400k threads, fully independent.
__global__ __launch_bounds__(256) void scatter_rank(const int2* __restrict__ rec,
                                                    const int* __restrict__ cnt,
                                                    const int* __restrict__ chunkoff,
                                                    int* __restrict__ elist) {
    const int i = (blockIdx.x * 256 + threadIdx.x) * 2;
    if (i < E_EDGES) {                               // E%2==0 -> pair in-bounds
        int4 r = *(const int4*)(rec + i);            // recs i, i+1
        int key0 = r.y & 0x7ffff, rank0 = (int)((unsigned)r.y >> 19);
        int key1 = r.w & 0x7ffff, rank1 = (int)((unsigned)r.w >> 19);
        elist[chunkoff[key0 >> 10] + cnt[key0] + rank0] = r.x;
        elist[chunkoff[key1 >> 10] + cnt[key1] + rank1] = r.z;
    }
}

// -------- fused conv: 256-thread blocks (4 waves), merged 4-dst stream/wave,
// 24-deep pipeline @ (256,6) -> ~85 VGPR budget, bf16 LDS tile, MFMA+ADV epilogue --------
// R12's VGPR_Count=32 showed the (256,8) 64-VGPR budget made the compiler break
// the 16-batch into shorter waitcnt groups; (256,6) trades cap 8->6 waves/SIMD
// (measured effective TLP was only ~4.6) for real 24-deep in-flight gathers.
#define FLUSH(P, V)                                                                   \
    { int _k = (P) >> 16;                                                             \
      if (_k != cur) { scat[cur >> 3][(cur & 7) * 64 + c] = f2bf(acc);                \
                       acc = 0.f; cur = _k; }                                         \
      acc += (V); }

#define EDGE(K)                                                                       \
    int p##K = __builtin_amdgcn_readlane(pv, e + K);                                  \
    float v##K = bf2f(Xb[(size_t)(p##K & 0xffff) * 64 + c]);

template <bool ADV>
__global__ __launch_bounds__(256, 6) void fused_conv(const unsigned short* __restrict__ Xb,
                                                     const unsigned short* __restrict__ WT,
                                                     const float* __restrict__ bias,
                                                     const int* __restrict__ cstart,   // start offsets
                                                     const int* __restrict__ chunkoff,
                                                     const int* __restrict__ elist,
                                                     unsigned short* __restrict__ Hb,
                                                     const unsigned short* __restrict__ Wa1T,
                                                     const float* __restrict__ ba1,
                                                     const unsigned short* __restrict__ Wa2T,
                                                     const float* __restrict__ ba2,
                                                     const unsigned short* __restrict__ h1r,
                                                     float* __restrict__ outF) {
    __shared__ __attribute__((aligned(16))) unsigned short scat[DPB][520];
    // adv-phase aliases over the scat pool (used only after a barrier)
    unsigned short (*sH)[72]  = (unsigned short(*)[72])&scat[0][0];          // 2304 B
    unsigned short (*sT)[136] = (unsigned short(*)[136])((char*)scat + 4096); // 4352 B
    const int lane = threadIdx.x & 63;
    const int wave = threadIdx.x >> 6;               // 0..3
    const int c = lane;
    const int dbase = blockIdx.x * DPB;

    {   // zero own 4 rows
        short8 z = {};
        *(short8*)&scat[wave * 4 + 0][lane * 8] = z;
        *(short8*)&scat[wave * 4 + 1][lane * 8] = z;
        *(short8*)&scat[wave * 4 + 2][lane * 8] = z;
        *(short8*)&scat[wave * 4 + 3][lane * 8] = z;
    }

    // contiguous stream for dst quad {dbase+4w .. dbase+4w+3}
    const int k0 = (dbase + wave * 4) * 8;
    const int k1 = k0 + 32;
    const int sbeg = chunkoff[k0 >> 10] + cstart[k0];
    const int send = (k1 >= KEYS) ? E_EDGES : chunkoff[k1 >> 10] + cstart[k1];
    int pv = (lane < send - sbeg) ? elist[sbeg + lane] : 0;

    {
        int i = sbeg;
        int cur = 0;
        float acc = 0.f;
        if (i < send) cur = __builtin_amdgcn_readlane(pv, 0) >> 16;
        while (i < send) {
            int cnt = send - i; cnt = (cnt > 64) ? 64 : cnt;
            int pvn = 0;
            if (i + 64 < send) pvn = (lane < send - i - 64) ? elist[i + 64 + lane] : 0;
            int e = 0;
            for (; e + 23 < cnt; e += 24) {          // 24 gathers in flight
                EDGE(0)  EDGE(1)  EDGE(2)  EDGE(3)
                EDGE(4)  EDGE(5)  EDGE(6)  EDGE(7)
                EDGE(8)  EDGE(9)  EDGE(10) EDGE(11)
                EDGE(12) EDGE(13) EDGE(14) EDGE(15)
                EDGE(16) EDGE(17) EDGE(18) EDGE(19)
                EDGE(20) EDGE(21) EDGE(22) EDGE(23)
                FLUSH(p0, v0)   FLUSH(p1, v1)   FLUSH(p2, v2)   FLUSH(p3, v3)
                FLUSH(p4, v4)   FLUSH(p5, v5)   FLUSH(p6, v6)   FLUSH(p7, v7)
                FLUSH(p8, v8)   FLUSH(p9, v9)   FLUSH(p10, v10) FLUSH(p11, v11)
                FLUSH(p12, v12) FLUSH(p13, v13) FLUSH(p14, v14) FLUSH(p15, v15)
                FLUSH(p16, v16) FLUSH(p17, v17) FLUSH(p18, v18) FLUSH(p19, v19)
                FLUSH(p20, v20) FLUSH(p21, v21) FLUSH(p22, v22) FLUSH(p23, v23)
            }
            if (e + 15 < cnt) {                      // tail tier 16
                EDGE(0)  EDGE(1)  EDGE(2)  EDGE(3)
                EDGE(4)  EDGE(5)  EDGE(6)  EDGE(7)
                EDGE(8)  EDGE(9)  EDGE(10) EDGE(11)
                EDGE(12) EDGE(13) EDGE(14) EDGE(15)
                FLUSH(p0, v0)   FLUSH(p1, v1)   FLUSH(p2, v2)   FLUSH(p3, v3)
                FLUSH(p4, v4)   FLUSH(p5, v5)   FLUSH(p6, v6)   FLUSH(p7, v7)
                FLUSH(p8, v8)   FLUSH(p9, v9)   FLUSH(p10, v10) FLUSH(p11, v11)
                FLUSH(p12, v12) FLUSH(p13, v13) FLUSH(p14, v14) FLUSH(p15, v15)
                e += 16;
            }
            if (e + 7 < cnt) {                       // tail tier 8
                EDGE(0) EDGE(1) EDGE(2) EDGE(3) EDGE(4) EDGE(5) EDGE(6) EDGE(7)
                FLUSH(p0, v0) FLUSH(p1, v1) FLUSH(p2, v2) FLUSH(p3, v3)
                FLUSH(p4, v4) FLUSH(p5, v5) FLUSH(p6, v6) FLUSH(p7, v7)
                e += 8;
            }
            if (e + 3 < cnt) {                       // tail tier 4
                EDGE(0) EDGE(1) EDGE(2) EDGE(3)
                FLUSH(p0, v0) FLUSH(p1, v1) FLUSH(p2, v2) FLUSH(p3, v3)
                e += 4;
            }
            if (e + 1 < cnt) {                       // tail tier 2
                EDGE(0) EDGE(1)
                FLUSH(p0, v0) FLUSH(p1, v1)
                e += 2;
            }
            if (e < cnt) {                           // tail tier 1
                EDGE(0)
                FLUSH(p0, v0)
            }
            i += 64;
            pv = pvn;
        }
        if (sbeg < send)
            scat[cur >> 3][(cur & 7) * 64 + c] = f2bf(acc);
    }
    __syncthreads();

    // MFMA [16,512]@[512,64] on all 4 waves; C/D col=lane&15, row=quad*4+r (m89/m91)
    const int m = lane & 15;
    const int quad = lane >> 4;
    f32x4 acc4 = {0.f, 0.f, 0.f, 0.f};
    {
        const int n0 = wave * 16;
        const unsigned short* wrow = WT + (size_t)(n0 + m) * 512;
        #pragma unroll
        for (int kc = 0; kc < 16; ++kc) {
            short8 af = *(const short8*)&scat[m][kc * 32 + quad * 8];
            short8 bf = *(const short8*)(wrow + kc * 32 + quad * 8);
            acc4 = __builtin_amdgcn_mfma_f32_16x16x32_bf16(af, bf, acc4, 0, 0, 0);
        }
    }

    if (!ADV) {
        const int col = wave * 16 + m;
        const float bcol = bias[col];
        #pragma unroll
        for (int r = 0; r < 4; ++r) {
            int node = dbase + quad * 4 + r;
            Hb[(size_t)node * 64 + col] = f2bf(fmaxf(acc4[r] + bcol, 0.f));
        }
    } else {
        // ---- fused adversary MLP on this tile's 16 nodes ----
        __syncthreads();                     // all scat MFMA reads complete
        {                                    // h2 (relu'd, bf16) -> sH
            const int col = wave * 16 + m;
            const float bcol = bias[col];
            #pragma unroll
            for (int r = 0; r < 4; ++r)
                sH[quad * 4 + r][col] = f2bf(fmaxf(acc4[r] + bcol, 0.f));
        }
        __syncthreads();
        {   // GEMM1: [16,64]@[64,128]; 4 waves x two 16-col tiles
            #pragma unroll
            for (int ct = 0; ct < 2; ++ct) {
                f32x4 a1 = {0.f, 0.f, 0.f, 0.f};
                const int col = (wave * 2 + ct) * 16 + m;
                #pragma unroll
                for (int kc = 0; kc < 2; ++kc) {
                    short8 af = *(const short8*)&sH[m][kc * 32 + quad * 8];
                    short8 bf = *(const short8*)(Wa1T + (size_t)col * 64 + kc * 32 + quad * 8);
                    a1 = __builtin_amdgcn_mfma_f32_16x16x32_bf16(af, bf, a1, 0, 0, 0);
                }
                const float b1 = ba1[col];
                #pragma unroll
                for (int r = 0; r < 4; ++r)
                    sT[quad * 4 + r][col] = f2bf(fmaxf(a1[r] + b1, 0.f));
            }
        }
        __syncthreads();
        {   // GEMM2: [16,128]@[128,64]; 4 waves x one 16-col tile; + ba2 + h1
            f32x4 a2 = {0.f, 0.f, 0.f, 0.f};
            const int col = wave * 16 + m;
            #pragma unroll
            for (int kc = 0; kc < 4; ++kc) {
                short8 af = *(const short8*)&sT[m][kc * 32 + quad * 8];
                short8 bf = *(const short8*)(Wa2T + (size_t)col * 128 + kc * 32 + quad * 8);
                a2 = __builtin_amdgcn_mfma_f32_16x16x32_bf16(af, bf, a2, 0, 0, 0);
            }
            const float b2 = ba2[col];
            #pragma unroll
            for (int r = 0; r < 4; ++r) {
                int node = dbase + quad * 4 + r;
                outF[(size_t)node * 64 + col] =
                    a2[r] + b2 + bf2f(h1r[(size_t)node * 64 + col]);
            }
        }
    }
}

extern "C" void kernel_launch(void* const* d_in, const int* in_sizes, int n_in,
                              void* d_out, int out_size, void* d_ws, size_t ws_size,
                              hipStream_t stream) {
    const float* x   = (const float*)d_in[0];
    const int*   ei  = (const int*)d_in[1];
    const int*   tix = (const int*)d_in[2];
    const float* Wt1 = (const float*)d_in[3];
    const float* bt1 = (const float*)d_in[4];
    const float* Wt2 = (const float*)d_in[5];
    const float* bt2 = (const float*)d_in[6];
    const float* Wa1 = (const float*)d_in[7];
    const float* ba1 = (const float*)d_in[8];
    const float* Wa2 = (const float*)d_in[9];
    const float* ba2 = (const float*)d_in[10];
    float* out = (float*)d_out;

    const int* src = ei;
    const int* dst = ei + E_EDGES;

    // workspace (~32 MB)
    unsigned short* xb   = (unsigned short*)d_ws;          // [N,64] bf16
    unsigned short* h1b  = xb + (size_t)N_NODES * 64;      // [N,64] bf16
    unsigned short* h2b  = h1b + (size_t)N_NODES * 64;     // [N,64] bf16 (unused)
    unsigned short* WT1  = h2b + (size_t)N_NODES * 64;     // [64,512] bf16
    unsigned short* WT2  = WT1 + 64 * 512;
    unsigned short* Wa1T = WT2 + 64 * 512;                 // [128,64] bf16
    unsigned short* Wa2T = Wa1T + 8192;                    // [64,128] bf16
    int* cnt      = (int*)(Wa2T + 8192);                   // KEYS
    int* bsum     = cnt + KEYS;                            // 512
    int* chunkoff = bsum + 512;                            // 512
    int* done     = chunkoff + 512;                        // 64 (1 used)
    int* elist    = done + 64;                             // E packed (src | t<<16 | dl<<19)
    int2* rec     = (int2*)(elist + E_EDGES);              // E records (payload, key|rank<<19)

    hipMemsetAsync(cnt, 0, (KEYS + 512 + 512 + 64) * sizeof(int), stream);
    prep_hist<<<PBLK_X + PBLK_W + PBLK_A + PBLK_H, 256, 0, stream>>>(
        x, Wt1, Wt2, Wa1, Wa2, src, dst, tix, xb, WT1, WT2, Wa1T, Wa2T, cnt, rec);
    scan_all<<<NBLK1, 256, 0, stream>>>(cnt, bsum, chunkoff, done);
    scatter_rank<<<(E_EDGES / 2 + 255) / 256, 256, 0, stream>>>(rec, cnt, chunkoff, elist);

    fused_conv<false><<<NTILES, 256, 0, stream>>>(
        xb, WT1, bt1, cnt, chunkoff, elist, h1b,
        nullptr, nullptr, nullptr, nullptr, nullptr, nullptr);
    fused_conv<true><<<NTILES, 256, 0, stream>>>(
        h1b, WT2, bt2, cnt, chunkoff, elist, nullptr,
        Wa1T, ba1, Wa2T, ba2, h1b, out);
}